// Round 1
// baseline (299.111 us; speedup 1.0000x reference)
//
#include <hip/hip_runtime.h>
#include <hip/hip_bf16.h>

// Problem constants: B=4, N=4096, DIM=1024; qkva = [B*N, 3*DIM]
#define SEQ_N 4096
#define BATCH 4
#define DIM 1024
#define M_ROWS (BATCH * SEQ_N)      // 16384
#define NCOLS (3 * DIM)             // 3072
#define KDIM DIM                    // 1024
#define CHUNK_L 32
#define NCHUNK (SEQ_N / CHUNK_L)    // 128
#define NCHANNEL (BATCH * DIM)      // 4096

using short8 = __attribute__((ext_vector_type(8))) short;
using f32x4  = __attribute__((ext_vector_type(4))) float;

static __device__ __forceinline__ unsigned short f2bf(float f) {
    union { float f; unsigned u; } v; v.f = f;
    unsigned r = v.u + 0x7fffu + ((v.u >> 16) & 1u);   // round-to-nearest-even
    return (unsigned short)(r >> 16);
}
static __device__ __forceinline__ float bf2f(unsigned short s) {
    union { unsigned u; float f; } v; v.u = ((unsigned)s) << 16;
    return v.f;
}
static __device__ __forceinline__ float sigm(float x) {
    return 1.f / (1.f + __expf(-x));
}

// ---------------- w fp32 -> bf16 ----------------
__global__ __launch_bounds__(256) void wconv_kernel(const float* __restrict__ in,
                                                    unsigned short* __restrict__ out,
                                                    int n4) {
    int i = blockIdx.x * 256 + threadIdx.x;
    if (i < n4) {
        float4 v = reinterpret_cast<const float4*>(in)[i];
        ushort4 o;
        o.x = f2bf(v.x); o.y = f2bf(v.y); o.z = f2bf(v.z); o.w = f2bf(v.w);
        reinterpret_cast<ushort4*>(out)[i] = o;
    }
}

// ---------------- RMSNorm (per row of 1024) -> bf16 ----------------
__global__ __launch_bounds__(256) void rmsnorm_kernel(const float* __restrict__ x,
                                                      const float* __restrict__ gamma,
                                                      unsigned short* __restrict__ h) {
    const int row = blockIdx.x;
    const int tid = threadIdx.x;
    const float4 v = reinterpret_cast<const float4*>(x + (size_t)row * DIM)[tid];
    float ss = v.x * v.x + v.y * v.y + v.z * v.z + v.w * v.w;
#pragma unroll
    for (int off = 32; off >= 1; off >>= 1) ss += __shfl_xor(ss, off, 64);
    __shared__ float red[4];
    if ((tid & 63) == 0) red[tid >> 6] = ss;
    __syncthreads();
    const float tot = red[0] + red[1] + red[2] + red[3];
    const float scale = 32.0f / fmaxf(sqrtf(tot), 1e-12f);   // sqrt(1024)=32
    const float4 g = reinterpret_cast<const float4*>(gamma)[tid];
    ushort4 o;
    o.x = f2bf(v.x * scale * g.x);
    o.y = f2bf(v.y * scale * g.y);
    o.z = f2bf(v.z * scale * g.z);
    o.w = f2bf(v.w * scale * g.w);
    reinterpret_cast<ushort4*>(h + (size_t)row * DIM)[tid] = o;
}

// ---------------- GEMM: C[m,e] = sum_k A[m,k] * B[e,k], bf16 in, bf16 out ----
// m97-style: 128x128 tile, BK=32, 4 waves (2x2 of 64x64), 16x16x32 bf16 MFMA,
// global_load_lds width-16 staging (LDS layout contiguous in tid order).
__global__ __launch_bounds__(256) void gemm_bt_kernel(const unsigned short* __restrict__ A,
                                                      const unsigned short* __restrict__ B,
                                                      unsigned short* __restrict__ C) {
    __shared__ __align__(16) unsigned short sA[128 * 32];
    __shared__ __align__(16) unsigned short sB[128 * 32];

    const int tid  = threadIdx.x;
    const int lane = tid & 63;
    const int wave = tid >> 6;
    const int row0 = blockIdx.y * 128;
    const int col0 = blockIdx.x * 128;
    const int wm = (wave >> 1) * 64;
    const int wn = (wave & 1) * 64;
    const int fr = lane & 15;   // frag row/col within 16x16
    const int kq = lane >> 4;   // k-quad (which 8 of K=32)

    const unsigned short* agp = A + (size_t)(row0 + (tid >> 2)) * KDIM + (tid & 3) * 8;
    const unsigned short* bgp = B + (size_t)(col0 + (tid >> 2)) * KDIM + (tid & 3) * 8;

    f32x4 acc[4][4] = {};

    for (int k0 = 0; k0 < KDIM; k0 += 32) {
        __builtin_amdgcn_global_load_lds(
            (const __attribute__((address_space(1))) void*)(agp),
            (__attribute__((address_space(3))) void*)(&sA[tid * 8]), 16, 0, 0);
        __builtin_amdgcn_global_load_lds(
            (const __attribute__((address_space(1))) void*)(agp + 64 * KDIM),
            (__attribute__((address_space(3))) void*)(&sA[2048 + tid * 8]), 16, 0, 0);
        __builtin_amdgcn_global_load_lds(
            (const __attribute__((address_space(1))) void*)(bgp),
            (__attribute__((address_space(3))) void*)(&sB[tid * 8]), 16, 0, 0);
        __builtin_amdgcn_global_load_lds(
            (const __attribute__((address_space(1))) void*)(bgp + 64 * KDIM),
            (__attribute__((address_space(3))) void*)(&sB[2048 + tid * 8]), 16, 0, 0);
        agp += 32; bgp += 32;
        __syncthreads();

        short8 af[4], bf[4];
#pragma unroll
        for (int i = 0; i < 4; ++i)
            af[i] = *reinterpret_cast<const short8*>(&sA[(wm + i * 16 + fr) * 32 + kq * 8]);
#pragma unroll
        for (int j = 0; j < 4; ++j)
            bf[j] = *reinterpret_cast<const short8*>(&sB[(wn + j * 16 + fr) * 32 + kq * 8]);
#pragma unroll
        for (int i = 0; i < 4; ++i)
#pragma unroll
            for (int j = 0; j < 4; ++j)
                acc[i][j] = __builtin_amdgcn_mfma_f32_16x16x32_bf16(af[i], bf[j], acc[i][j], 0, 0, 0);
        __syncthreads();
    }

    // epilogue: C/D layout col=lane&15, row=(lane>>4)*4+reg
#pragma unroll
    for (int i = 0; i < 4; ++i) {
#pragma unroll
        for (int j = 0; j < 4; ++j) {
#pragma unroll
            for (int r = 0; r < 4; ++r) {
                int row = row0 + wm + i * 16 + kq * 4 + r;
                int col = col0 + wn + j * 16 + fr;
                C[(size_t)row * NCOLS + col] = f2bf(acc[i][j][r]);
            }
        }
    }
}

// ---------------- Scan phase 1: per-chunk aggregates (A = prod a, Y = local state)
// 4 channels/thread, ushort4 (8B) loads. Grid: (NCHUNK, BATCH), 256 threads.
__global__ __launch_bounds__(256) void chunk_agg_kernel(const unsigned short* __restrict__ qkva,
                                                        float* __restrict__ Aagg,
                                                        float* __restrict__ Yagg) {
    const int c = blockIdx.x, b = blockIdx.y;
    const int d4 = threadIdx.x * 4;                  // channel group base (0..1020)
    const unsigned short* base = qkva + ((size_t)b * SEQ_N + c * CHUNK_L) * NCOLS;
    float s[4] = {0.f, 0.f, 0.f, 0.f};
    float A[4] = {1.f, 1.f, 1.f, 1.f};
#pragma unroll 4
    for (int n = 0; n < CHUNK_L; ++n) {
        const ushort4 kvu = *reinterpret_cast<const ushort4*>(base + (size_t)n * NCOLS + DIM + d4);
        const ushort4 au  = *reinterpret_cast<const ushort4*>(base + (size_t)n * NCOLS + 2 * DIM + d4);
        const float kv[4] = {bf2f(kvu.x), bf2f(kvu.y), bf2f(kvu.z), bf2f(kvu.w)};
        const float av[4] = {bf2f(au.x),  bf2f(au.y),  bf2f(au.z),  bf2f(au.w)};
#pragma unroll
        for (int j = 0; j < 4; ++j) {
            const float a = sigm(av[j]);
            s[j] = fmaf(a, s[j], kv[j]);
            A[j] *= a;
        }
    }
    const int idx = c * NCHANNEL + b * DIM + d4;
    float4 Ao, Yo;
    Ao.x = A[0]; Ao.y = A[1]; Ao.z = A[2]; Ao.w = A[3];
    Yo.x = s[0]; Yo.y = s[1]; Yo.z = s[2]; Yo.w = s[3];
    *reinterpret_cast<float4*>(&Aagg[idx]) = Ao;
    *reinterpret_cast<float4*>(&Yagg[idx]) = Yo;
}

// ---------------- Scan phase 2: sequential scan over chunk aggregates -> chunk entry state
__global__ __launch_bounds__(256) void agg_scan_kernel(const float* __restrict__ Aagg,
                                                       const float* __restrict__ Yagg,
                                                       float* __restrict__ Sin) {
    const int ch = blockIdx.x * 256 + threadIdx.x;   // 0..4095
    float s = 0.f;
#pragma unroll 8
    for (int c = 0; c < NCHUNK; ++c) {
        const float A = Aagg[c * NCHANNEL + ch];
        const float Y = Yagg[c * NCHANNEL + ch];
        Sin[c * NCHANNEL + ch] = s;
        s = fmaf(A, s, Y);
    }
}

// ---------------- Scan phase 3: rescan chunk with correct entry state, out = q*y
// 4 channels/thread, ushort4 loads + float4 store. Grid: (NCHUNK, BATCH), 256 threads.
__global__ __launch_bounds__(256) void apply_kernel(const unsigned short* __restrict__ qkva,
                                                    const float* __restrict__ Sin,
                                                    float* __restrict__ out) {
    const int c = blockIdx.x, b = blockIdx.y;
    const int d4 = threadIdx.x * 4;
    const unsigned short* base = qkva + ((size_t)b * SEQ_N + c * CHUNK_L) * NCOLS;
    float* obase = out + ((size_t)b * SEQ_N + c * CHUNK_L) * DIM;
    const float4 s0 = *reinterpret_cast<const float4*>(&Sin[c * NCHANNEL + b * DIM + d4]);
    float s[4] = {s0.x, s0.y, s0.z, s0.w};
#pragma unroll 2
    for (int n = 0; n < CHUNK_L; ++n) {
        const ushort4 qu  = *reinterpret_cast<const ushort4*>(base + (size_t)n * NCOLS + d4);
        const ushort4 kvu = *reinterpret_cast<const ushort4*>(base + (size_t)n * NCOLS + DIM + d4);
        const ushort4 au  = *reinterpret_cast<const ushort4*>(base + (size_t)n * NCOLS + 2 * DIM + d4);
        const float kv[4] = {bf2f(kvu.x), bf2f(kvu.y), bf2f(kvu.z), bf2f(kvu.w)};
        const float av[4] = {bf2f(au.x),  bf2f(au.y),  bf2f(au.z),  bf2f(au.w)};
        const float q[4]  = {bf2f(qu.x),  bf2f(qu.y),  bf2f(qu.z),  bf2f(qu.w)};
        float4 o;
#pragma unroll
        for (int j = 0; j < 4; ++j) {
            const float a = sigm(av[j]);
            s[j] = fmaf(a, s[j], kv[j]);
        }
        o.x = q[0] * s[0]; o.y = q[1] * s[1]; o.z = q[2] * s[2]; o.w = q[3] * s[3];
        *reinterpret_cast<float4*>(&obase[(size_t)n * DIM + d4]) = o;
    }
}

extern "C" void kernel_launch(void* const* d_in, const int* in_sizes, int n_in,
                              void* d_out, int out_size, void* d_ws, size_t ws_size,
                              hipStream_t stream) {
    const float* x     = (const float*)d_in[0];   // [4,4096,1024]
    const float* w     = (const float*)d_in[1];   // [3072,1024]
    const float* gamma = (const float*)d_in[2];   // [1024]
    float* out = (float*)d_out;                   // [4,4096,1024]

    char* ws = (char*)d_ws;
    // workspace layout (bytes):
    unsigned short* wb   = (unsigned short*)(ws);                         // 3072*1024*2   = 6,291,456
    unsigned short* h    = (unsigned short*)(ws + 6291456);               // 16384*1024*2  = 33,554,432
    unsigned short* qkva = (unsigned short*)(ws + 39845888);              // 16384*3072*2  = 100,663,296
    // scan temporaries alias the h region (h is dead after the GEMM):
    // NCHUNK*NCHANNEL*4 = 128*4096*4 = 2,097,152 each
    float* Aagg = (float*)(ws + 6291456);
    float* Yagg = (float*)(ws + 6291456 + 2097152);
    float* Sin  = (float*)(ws + 6291456 + 4194304);
    // total ws usage: 140,509,184 bytes

    wconv_kernel<<<(NCOLS * KDIM / 4 + 255) / 256, 256, 0, stream>>>(w, wb, NCOLS * KDIM / 4);
    rmsnorm_kernel<<<M_ROWS, 256, 0, stream>>>(x, gamma, h);
    gemm_bt_kernel<<<dim3(NCOLS / 128, M_ROWS / 128), 256, 0, stream>>>(h, wb, qkva);
    chunk_agg_kernel<<<dim3(NCHUNK, BATCH), 256, 0, stream>>>(qkva, Aagg, Yagg);
    agg_scan_kernel<<<NCHANNEL / 256, 256, 0, stream>>>(Aagg, Yagg, Sin);
    apply_kernel<<<dim3(NCHUNK, BATCH), 256, 0, stream>>>(qkva, Sin, out);
}

// Round 2
// 296.935 us; speedup vs baseline: 1.0073x; 1.0073x over previous
//
#include <hip/hip_runtime.h>
#include <hip/hip_bf16.h>

// Problem constants: B=4, N=4096, DIM=1024; qkva = [B*N, 3*DIM]
#define SEQ_N 4096
#define BATCH 4
#define DIM 1024
#define M_ROWS (BATCH * SEQ_N)      // 16384
#define NCOLS (3 * DIM)             // 3072
#define KDIM DIM                    // 1024
#define CHUNK_L 32
#define NCHUNK (SEQ_N / CHUNK_L)    // 128
#define NCHANNEL (BATCH * DIM)      // 4096
#define GT 32                       // K / 32 k-tiles for the 256x256 GEMM

using short8 = __attribute__((ext_vector_type(8))) short;
using f32x4  = __attribute__((ext_vector_type(4))) float;

static __device__ __forceinline__ unsigned short f2bf(float f) {
    union { float f; unsigned u; } v; v.f = f;
    unsigned r = v.u + 0x7fffu + ((v.u >> 16) & 1u);   // round-to-nearest-even
    return (unsigned short)(r >> 16);
}
static __device__ __forceinline__ float bf2f(unsigned short s) {
    union { unsigned u; float f; } v; v.u = ((unsigned)s) << 16;
    return v.f;
}
static __device__ __forceinline__ float sigm(float x) {
    return 1.f / (1.f + __expf(-x));
}

// ---------------- w fp32 -> bf16 ----------------
__global__ __launch_bounds__(256) void wconv_kernel(const float* __restrict__ in,
                                                    unsigned short* __restrict__ out,
                                                    int n4) {
    int i = blockIdx.x * 256 + threadIdx.x;
    if (i < n4) {
        float4 v = reinterpret_cast<const float4*>(in)[i];
        ushort4 o;
        o.x = f2bf(v.x); o.y = f2bf(v.y); o.z = f2bf(v.z); o.w = f2bf(v.w);
        reinterpret_cast<ushort4*>(out)[i] = o;
    }
}

// ---------------- RMSNorm (per row of 1024) -> bf16 ----------------
__global__ __launch_bounds__(256) void rmsnorm_kernel(const float* __restrict__ x,
                                                      const float* __restrict__ gamma,
                                                      unsigned short* __restrict__ h) {
    const int row = blockIdx.x;
    const int tid = threadIdx.x;
    const float4 v = reinterpret_cast<const float4*>(x + (size_t)row * DIM)[tid];
    float ss = v.x * v.x + v.y * v.y + v.z * v.z + v.w * v.w;
#pragma unroll
    for (int off = 32; off >= 1; off >>= 1) ss += __shfl_xor(ss, off, 64);
    __shared__ float red[4];
    if ((tid & 63) == 0) red[tid >> 6] = ss;
    __syncthreads();
    const float tot = red[0] + red[1] + red[2] + red[3];
    const float scale = 32.0f / fmaxf(sqrtf(tot), 1e-12f);   // sqrt(1024)=32
    const float4 g = reinterpret_cast<const float4*>(gamma)[tid];
    ushort4 o;
    o.x = f2bf(v.x * scale * g.x);
    o.y = f2bf(v.y * scale * g.y);
    o.z = f2bf(v.z * scale * g.z);
    o.w = f2bf(v.w * scale * g.w);
    reinterpret_cast<ushort4*>(h + (size_t)row * DIM)[tid] = o;
}

// ---------------- GEMM: C[m,e] = sum_k A[m,k] * B[e,k], bf16 in, bf16 out ----
// 256x256 tile, BK=32, 4-deep LDS buffer rotation, 8 waves (2Mx4N),
// per-phase {ds_read || gload_lds issue || 16 MFMA}, counted vmcnt(4) at tile
// boundaries (T3+T4), setprio around MFMA (T5), bijective XCD swizzle (T1).
// BK=32 => 64B LDS row stride => ds_read_b128 is bank-conflict-optimal with a
// LINEAR layout, so global_load_lds (linear dest) needs no swizzle (rule #21).
__global__ __launch_bounds__(512, 2) void gemm256_kernel(const unsigned short* __restrict__ A,
                                                         const unsigned short* __restrict__ B,
                                                         unsigned short* __restrict__ C) {
    __shared__ __align__(16) unsigned short sA[4][256][32];   // 64 KiB
    __shared__ __align__(16) unsigned short sB[4][256][32];   // 64 KiB

    const int tid  = threadIdx.x;
    const int lane = tid & 63;
    const int wave = tid >> 6;

    // T1: bijective XCD swizzle (nwg = 768 = 8 * 96)
    const int orig = blockIdx.x;
    const int swz  = (orig & 7) * 96 + (orig >> 3);
    const int ntile = swz >> 6;           // 0..11  (swz / 64)
    const int mtile = swz & 63;           // 0..63
    const int row0 = mtile * 256;
    const int col0 = ntile * 256;

    const int wm = (wave >> 2) * 128;     // 0 or 128
    const int wn = (wave & 3) * 64;       // 0,64,128,192
    const int fr = lane & 15;             // frag row/col within 16x16
    const int kq = lane >> 4;             // k-quad (which 8 of K=32)

    // staging addressing: 512 thr x 16B = 8KB per load-unit; 2 units (u) cover
    // 128 rows each; 4 loads per k-tile (A u0,u1 + B u0,u1)
    const int srow = tid >> 2;            // 0..127
    const int scol = (tid & 3) * 8;       // 0,8,16,24 (elements)
    const unsigned short* aSrc = A + (size_t)(row0 + srow) * KDIM + scol;
    const unsigned short* bSrc = B + (size_t)(col0 + srow) * KDIM + scol;
    unsigned short* sAf = &sA[0][0][0];
    unsigned short* sBf = &sB[0][0][0];
    const int sdst = tid * 8;             // element offset within an 8KB unit

#define STAGE_A(bs, kt, u)                                                              \
    __builtin_amdgcn_global_load_lds(                                                   \
        (const __attribute__((address_space(1))) void*)(aSrc + (size_t)(u) * 128 * KDIM + (kt) * 32), \
        (__attribute__((address_space(3))) void*)(sAf + (bs) * 8192 + (u) * 4096 + sdst), 16, 0, 0);
#define STAGE_B(bs, kt, u)                                                              \
    __builtin_amdgcn_global_load_lds(                                                   \
        (const __attribute__((address_space(1))) void*)(bSrc + (size_t)(u) * 128 * KDIM + (kt) * 32), \
        (__attribute__((address_space(3))) void*)(sBf + (bs) * 8192 + (u) * 4096 + sdst), 16, 0, 0);

    f32x4 acc[8][4] = {};

    // prologue: stage tiles 0 and 1 (8 loads), wait for tile 0 (4 left in flight)
    STAGE_A(0, 0, 0); STAGE_A(0, 0, 1); STAGE_B(0, 0, 0); STAGE_B(0, 0, 1);
    STAGE_A(1, 1, 0); STAGE_A(1, 1, 1); STAGE_B(1, 1, 0); STAGE_B(1, 1, 1);
    asm volatile("s_waitcnt vmcnt(4)" ::: "memory");
    __builtin_amdgcn_sched_barrier(0);
    __builtin_amdgcn_s_barrier();

    // invariant entering tile t: tiles <= t landed; only tile t+1's 4 loads outstanding
    for (int t = 0; t < GT; ++t) {
        const int b  = t & 3;
        const int bs = (t + 2) & 3;
        const bool st = (t + 2 < GT);
        const unsigned short* sAb = sAf + b * 8192;
        const unsigned short* sBb = sBf + b * 8192;

        // ---- phase 0: C-frags i=0..3 (rows wm..wm+63) ----
        short8 bfr[4], afr[4];
#pragma unroll
        for (int j = 0; j < 4; ++j)
            bfr[j] = *reinterpret_cast<const short8*>(sBb + (wn + j * 16 + fr) * 32 + kq * 8);
#pragma unroll
        for (int i = 0; i < 4; ++i)
            afr[i] = *reinterpret_cast<const short8*>(sAb + (wm + i * 16 + fr) * 32 + kq * 8);
        if (st) { STAGE_A(bs, t + 2, 0); STAGE_A(bs, t + 2, 1); }
        __builtin_amdgcn_s_barrier();
        __builtin_amdgcn_s_setprio(1);
#pragma unroll
        for (int i = 0; i < 4; ++i)
#pragma unroll
            for (int j = 0; j < 4; ++j)
                acc[i][j] = __builtin_amdgcn_mfma_f32_16x16x32_bf16(afr[i], bfr[j], acc[i][j], 0, 0, 0);
        __builtin_amdgcn_s_setprio(0);
        __builtin_amdgcn_s_barrier();

        // ---- phase 1: C-frags i=4..7 (rows wm+64..wm+127), reuse bfr ----
        short8 afr2[4];
#pragma unroll
        for (int i = 0; i < 4; ++i)
            afr2[i] = *reinterpret_cast<const short8*>(sAb + (wm + 64 + i * 16 + fr) * 32 + kq * 8);
        if (st) { STAGE_B(bs, t + 2, 0); STAGE_B(bs, t + 2, 1); }
        __builtin_amdgcn_s_barrier();
        __builtin_amdgcn_s_setprio(1);
#pragma unroll
        for (int i = 0; i < 4; ++i)
#pragma unroll
            for (int j = 0; j < 4; ++j)
                acc[4 + i][j] = __builtin_amdgcn_mfma_f32_16x16x32_bf16(afr2[i], bfr[j], acc[4 + i][j], 0, 0, 0);
        __builtin_amdgcn_s_setprio(0);
        // counted vmcnt: tile t+1's 4 loads must have landed; t+2's 4 stay in flight
        if (t < GT - 2) {
            asm volatile("s_waitcnt vmcnt(4)" ::: "memory");
        } else if (t == GT - 2) {
            asm volatile("s_waitcnt vmcnt(0)" ::: "memory");
        }
        __builtin_amdgcn_sched_barrier(0);
        __builtin_amdgcn_s_barrier();
    }
#undef STAGE_A
#undef STAGE_B

    // epilogue: C/D layout col=lane&15, row=(lane>>4)*4+reg
#pragma unroll
    for (int i = 0; i < 8; ++i) {
#pragma unroll
        for (int j = 0; j < 4; ++j) {
#pragma unroll
            for (int r = 0; r < 4; ++r) {
                int row = row0 + wm + i * 16 + kq * 4 + r;
                int col = col0 + wn + j * 16 + fr;
                C[(size_t)row * NCOLS + col] = f2bf(acc[i][j][r]);
            }
        }
    }
}

// ---------------- Scan phase 1: per-chunk aggregates (A = prod a, Y = local state)
__global__ __launch_bounds__(256) void chunk_agg_kernel(const unsigned short* __restrict__ qkva,
                                                        float* __restrict__ Aagg,
                                                        float* __restrict__ Yagg) {
    const int c = blockIdx.x, b = blockIdx.y;
    const int d4 = threadIdx.x * 4;                  // channel group base (0..1020)
    const unsigned short* base = qkva + ((size_t)b * SEQ_N + c * CHUNK_L) * NCOLS;
    float s[4] = {0.f, 0.f, 0.f, 0.f};
    float A[4] = {1.f, 1.f, 1.f, 1.f};
#pragma unroll 4
    for (int n = 0; n < CHUNK_L; ++n) {
        const ushort4 kvu = *reinterpret_cast<const ushort4*>(base + (size_t)n * NCOLS + DIM + d4);
        const ushort4 au  = *reinterpret_cast<const ushort4*>(base + (size_t)n * NCOLS + 2 * DIM + d4);
        const float kv[4] = {bf2f(kvu.x), bf2f(kvu.y), bf2f(kvu.z), bf2f(kvu.w)};
        const float av[4] = {bf2f(au.x),  bf2f(au.y),  bf2f(au.z),  bf2f(au.w)};
#pragma unroll
        for (int j = 0; j < 4; ++j) {
            const float a = sigm(av[j]);
            s[j] = fmaf(a, s[j], kv[j]);
            A[j] *= a;
        }
    }
    const int idx = c * NCHANNEL + b * DIM + d4;
    float4 Ao, Yo;
    Ao.x = A[0]; Ao.y = A[1]; Ao.z = A[2]; Ao.w = A[3];
    Yo.x = s[0]; Yo.y = s[1]; Yo.z = s[2]; Yo.w = s[3];
    *reinterpret_cast<float4*>(&Aagg[idx]) = Ao;
    *reinterpret_cast<float4*>(&Yagg[idx]) = Yo;
}

// ---------------- Scan phase 2: sequential scan over chunk aggregates -> chunk entry state
__global__ __launch_bounds__(256) void agg_scan_kernel(const float* __restrict__ Aagg,
                                                       const float* __restrict__ Yagg,
                                                       float* __restrict__ Sin) {
    const int ch = blockIdx.x * 256 + threadIdx.x;   // 0..4095
    float s = 0.f;
#pragma unroll 8
    for (int c = 0; c < NCHUNK; ++c) {
        const float A = Aagg[c * NCHANNEL + ch];
        const float Y = Yagg[c * NCHANNEL + ch];
        Sin[c * NCHANNEL + ch] = s;
        s = fmaf(A, s, Y);
    }
}

// ---------------- Scan phase 3: rescan chunk with correct entry state, out = q*y
__global__ __launch_bounds__(256) void apply_kernel(const unsigned short* __restrict__ qkva,
                                                    const float* __restrict__ Sin,
                                                    float* __restrict__ out) {
    const int c = blockIdx.x, b = blockIdx.y;
    const int d4 = threadIdx.x * 4;
    const unsigned short* base = qkva + ((size_t)b * SEQ_N + c * CHUNK_L) * NCOLS;
    float* obase = out + ((size_t)b * SEQ_N + c * CHUNK_L) * DIM;
    const float4 s0 = *reinterpret_cast<const float4*>(&Sin[c * NCHANNEL + b * DIM + d4]);
    float s[4] = {s0.x, s0.y, s0.z, s0.w};
#pragma unroll 2
    for (int n = 0; n < CHUNK_L; ++n) {
        const ushort4 qu  = *reinterpret_cast<const ushort4*>(base + (size_t)n * NCOLS + d4);
        const ushort4 kvu = *reinterpret_cast<const ushort4*>(base + (size_t)n * NCOLS + DIM + d4);
        const ushort4 au  = *reinterpret_cast<const ushort4*>(base + (size_t)n * NCOLS + 2 * DIM + d4);
        const float kv[4] = {bf2f(kvu.x), bf2f(kvu.y), bf2f(kvu.z), bf2f(kvu.w)};
        const float av[4] = {bf2f(au.x),  bf2f(au.y),  bf2f(au.z),  bf2f(au.w)};
        const float q[4]  = {bf2f(qu.x),  bf2f(qu.y),  bf2f(qu.z),  bf2f(qu.w)};
        float4 o;
#pragma unroll
        for (int j = 0; j < 4; ++j) {
            const float a = sigm(av[j]);
            s[j] = fmaf(a, s[j], kv[j]);
        }
        o.x = q[0] * s[0]; o.y = q[1] * s[1]; o.z = q[2] * s[2]; o.w = q[3] * s[3];
        *reinterpret_cast<float4*>(&obase[(size_t)n * DIM + d4]) = o;
    }
}

extern "C" void kernel_launch(void* const* d_in, const int* in_sizes, int n_in,
                              void* d_out, int out_size, void* d_ws, size_t ws_size,
                              hipStream_t stream) {
    const float* x     = (const float*)d_in[0];   // [4,4096,1024]
    const float* w     = (const float*)d_in[1];   // [3072,1024]
    const float* gamma = (const float*)d_in[2];   // [1024]
    float* out = (float*)d_out;                   // [4,4096,1024]

    char* ws = (char*)d_ws;
    // workspace layout (bytes):
    unsigned short* wb   = (unsigned short*)(ws);                         // 3072*1024*2   = 6,291,456
    unsigned short* h    = (unsigned short*)(ws + 6291456);               // 16384*1024*2  = 33,554,432
    unsigned short* qkva = (unsigned short*)(ws + 39845888);              // 16384*3072*2  = 100,663,296
    // scan temporaries alias the h region (h is dead after the GEMM):
    float* Aagg = (float*)(ws + 6291456);
    float* Yagg = (float*)(ws + 6291456 + 2097152);
    float* Sin  = (float*)(ws + 6291456 + 4194304);

    wconv_kernel<<<(NCOLS * KDIM / 4 + 255) / 256, 256, 0, stream>>>(w, wb, NCOLS * KDIM / 4);
    rmsnorm_kernel<<<M_ROWS, 256, 0, stream>>>(x, gamma, h);
    gemm256_kernel<<<(M_ROWS / 256) * (NCOLS / 256), 512, 0, stream>>>(h, wb, qkva);
    chunk_agg_kernel<<<dim3(NCHUNK, BATCH), 256, 0, stream>>>(qkva, Aagg, Yagg);
    agg_scan_kernel<<<NCHANNEL / 256, 256, 0, stream>>>(Aagg, Yagg, Sin);
    apply_kernel<<<dim3(NCHUNK, BATCH), 256, 0, stream>>>(qkva, Sin, out);
}

// Round 3
// 294.340 us; speedup vs baseline: 1.0162x; 1.0088x over previous
//
#include <hip/hip_runtime.h>
#include <hip/hip_bf16.h>

// Problem constants: B=4, N=4096, DIM=1024; qkva = [B*N, 3*DIM]
#define SEQ_N 4096
#define BATCH 4
#define DIM 1024
#define M_ROWS (BATCH * SEQ_N)      // 16384
#define NCOLS (3 * DIM)             // 3072
#define KDIM DIM                    // 1024
#define CHUNK_L 16
#define NCHUNK (SEQ_N / CHUNK_L)    // 256
#define NCHANNEL (BATCH * DIM)      // 4096
#define GT 32                       // K / 32 k-tiles for the 256x256 GEMM

using short8 = __attribute__((ext_vector_type(8))) short;
using f32x4  = __attribute__((ext_vector_type(4))) float;

static __device__ __forceinline__ unsigned short f2bf(float f) {
    union { float f; unsigned u; } v; v.f = f;
    unsigned r = v.u + 0x7fffu + ((v.u >> 16) & 1u);   // round-to-nearest-even
    return (unsigned short)(r >> 16);
}
static __device__ __forceinline__ float bf2f(unsigned short s) {
    union { unsigned u; float f; } v; v.u = ((unsigned)s) << 16;
    return v.f;
}
static __device__ __forceinline__ float sigm(float x) {
    return 1.f / (1.f + __expf(-x));
}

// ---------------- fused: w fp32->bf16 (blocks 0..3071) + RMSNorm (blocks 3072..) ----
#define WCONV_BLOCKS 3072           // NCOLS*KDIM/4/256
__global__ __launch_bounds__(256) void pre_kernel(const float* __restrict__ w,
                                                  unsigned short* __restrict__ wb,
                                                  const float* __restrict__ x,
                                                  const float* __restrict__ gamma,
                                                  unsigned short* __restrict__ h) {
    const int bid = blockIdx.x;
    const int tid = threadIdx.x;
    if (bid < WCONV_BLOCKS) {
        const int i = bid * 256 + tid;
        float4 v = reinterpret_cast<const float4*>(w)[i];
        ushort4 o;
        o.x = f2bf(v.x); o.y = f2bf(v.y); o.z = f2bf(v.z); o.w = f2bf(v.w);
        reinterpret_cast<ushort4*>(wb)[i] = o;
        return;
    }
    const int row = bid - WCONV_BLOCKS;
    const float4 v = reinterpret_cast<const float4*>(x + (size_t)row * DIM)[tid];
    float ss = v.x * v.x + v.y * v.y + v.z * v.z + v.w * v.w;
#pragma unroll
    for (int off = 32; off >= 1; off >>= 1) ss += __shfl_xor(ss, off, 64);
    __shared__ float red[4];
    if ((tid & 63) == 0) red[tid >> 6] = ss;
    __syncthreads();
    const float tot = red[0] + red[1] + red[2] + red[3];
    const float scale = 32.0f / fmaxf(sqrtf(tot), 1e-12f);   // sqrt(1024)=32
    const float4 g = reinterpret_cast<const float4*>(gamma)[tid];
    ushort4 o;
    o.x = f2bf(v.x * scale * g.x);
    o.y = f2bf(v.y * scale * g.y);
    o.z = f2bf(v.z * scale * g.z);
    o.w = f2bf(v.w * scale * g.w);
    reinterpret_cast<ushort4*>(h + (size_t)row * DIM)[tid] = o;
}

// ---------------- GEMM: C[m,e] = sum_k A[m,k] * B[e,k], bf16 in, bf16 out ----
// 256x256 tile, BK=32, 4-deep LDS rotation, 8 waves (2Mx4N), counted vmcnt(4)
// (T3+T4), setprio (T5), bijective XCD swizzle (T1), and T2: 16B-granule XOR
// swizzle slot(r,g) <-> global granule g^((r>>1)&3), applied on the GLOBAL
// source (LDS dest stays linear for global_load_lds) and identically on the
// ds_read side (rule #21). Read-side XOR folds to a per-lane constant kqx
// because wm/wn/i*16/j*16 are multiples of 16.
__global__ __launch_bounds__(512, 2) void gemm256_kernel(const unsigned short* __restrict__ A,
                                                         const unsigned short* __restrict__ B,
                                                         unsigned short* __restrict__ C) {
    __shared__ __align__(16) unsigned short sA[4][256][32];   // 64 KiB
    __shared__ __align__(16) unsigned short sB[4][256][32];   // 64 KiB

    const int tid  = threadIdx.x;
    const int lane = tid & 63;
    const int wave = tid >> 6;

    // T1: bijective XCD swizzle (nwg = 768 = 8 * 96)
    const int orig = blockIdx.x;
    const int swz  = (orig & 7) * 96 + (orig >> 3);
    const int ntile = swz >> 6;           // 0..11
    const int mtile = swz & 63;           // 0..63
    const int row0 = mtile * 256;
    const int col0 = ntile * 256;

    const int wm = (wave >> 2) * 128;     // 0 or 128
    const int wn = (wave & 3) * 64;       // 0,64,128,192
    const int fr = lane & 15;             // frag row/col within 16x16
    const int kq = lane >> 4;             // k-quad (which 8 of K=32)
    const int kqx = kq ^ ((fr >> 1) & 3); // T2 swizzled granule (per-lane const)

    // staging: 512 thr x 16B = 8KB per unit; unit covers 128 rows; T2 source perm
    const int srow = tid >> 2;            // 0..127
    const int scol = ((tid & 3) ^ ((srow >> 1) & 3)) * 8;   // swizzled global granule
    const unsigned short* aSrc = A + (size_t)(row0 + srow) * KDIM + scol;
    const unsigned short* bSrc = B + (size_t)(col0 + srow) * KDIM + scol;
    unsigned short* sAf = &sA[0][0][0];
    unsigned short* sBf = &sB[0][0][0];
    const int sdst = tid * 8;             // linear LDS dest (element offset)

#define STAGE_A(bs, kt, u)                                                              \
    __builtin_amdgcn_global_load_lds(                                                   \
        (const __attribute__((address_space(1))) void*)(aSrc + (size_t)(u) * 128 * KDIM + (kt) * 32), \
        (__attribute__((address_space(3))) void*)(sAf + (bs) * 8192 + (u) * 4096 + sdst), 16, 0, 0);
#define STAGE_B(bs, kt, u)                                                              \
    __builtin_amdgcn_global_load_lds(                                                   \
        (const __attribute__((address_space(1))) void*)(bSrc + (size_t)(u) * 128 * KDIM + (kt) * 32), \
        (__attribute__((address_space(3))) void*)(sBf + (bs) * 8192 + (u) * 4096 + sdst), 16, 0, 0);

    f32x4 acc[8][4] = {};

    // prologue: stage tiles 0 and 1 (8 loads), wait for tile 0 (4 left in flight)
    STAGE_A(0, 0, 0); STAGE_A(0, 0, 1); STAGE_B(0, 0, 0); STAGE_B(0, 0, 1);
    STAGE_A(1, 1, 0); STAGE_A(1, 1, 1); STAGE_B(1, 1, 0); STAGE_B(1, 1, 1);
    asm volatile("s_waitcnt vmcnt(4)" ::: "memory");
    __builtin_amdgcn_sched_barrier(0);
    __builtin_amdgcn_s_barrier();

    // invariant entering tile t: tiles <= t landed; only tile t+1's 4 loads outstanding
    for (int t = 0; t < GT; ++t) {
        const int b  = t & 3;
        const int bs = (t + 2) & 3;
        const bool st = (t + 2 < GT);
        const unsigned short* sAb = sAf + b * 8192;
        const unsigned short* sBb = sBf + b * 8192;

        // ---- phase 0: C-frags i=0..3 (rows wm..wm+63) ----
        short8 bfr[4], afr[4];
#pragma unroll
        for (int j = 0; j < 4; ++j)
            bfr[j] = *reinterpret_cast<const short8*>(sBb + (wn + j * 16 + fr) * 32 + kqx * 8);
#pragma unroll
        for (int i = 0; i < 4; ++i)
            afr[i] = *reinterpret_cast<const short8*>(sAb + (wm + i * 16 + fr) * 32 + kqx * 8);
        if (st) { STAGE_A(bs, t + 2, 0); STAGE_A(bs, t + 2, 1); }
        __builtin_amdgcn_s_barrier();
        __builtin_amdgcn_s_setprio(1);
#pragma unroll
        for (int i = 0; i < 4; ++i)
#pragma unroll
            for (int j = 0; j < 4; ++j)
                acc[i][j] = __builtin_amdgcn_mfma_f32_16x16x32_bf16(afr[i], bfr[j], acc[i][j], 0, 0, 0);
        __builtin_amdgcn_s_setprio(0);
        __builtin_amdgcn_s_barrier();

        // ---- phase 1: C-frags i=4..7 (rows wm+64..wm+127), reuse bfr ----
        short8 afr2[4];
#pragma unroll
        for (int i = 0; i < 4; ++i)
            afr2[i] = *reinterpret_cast<const short8*>(sAb + (wm + 64 + i * 16 + fr) * 32 + kqx * 8);
        if (st) { STAGE_B(bs, t + 2, 0); STAGE_B(bs, t + 2, 1); }
        __builtin_amdgcn_s_barrier();
        __builtin_amdgcn_s_setprio(1);
#pragma unroll
        for (int i = 0; i < 4; ++i)
#pragma unroll
            for (int j = 0; j < 4; ++j)
                acc[4 + i][j] = __builtin_amdgcn_mfma_f32_16x16x32_bf16(afr2[i], bfr[j], acc[4 + i][j], 0, 0, 0);
        __builtin_amdgcn_s_setprio(0);
        // counted vmcnt: tile t+1's 4 loads must have landed; t+2's 4 stay in flight
        if (t < GT - 2) {
            asm volatile("s_waitcnt vmcnt(4)" ::: "memory");
        } else if (t == GT - 2) {
            asm volatile("s_waitcnt vmcnt(0)" ::: "memory");
        }
        __builtin_amdgcn_sched_barrier(0);
        __builtin_amdgcn_s_barrier();
    }
#undef STAGE_A
#undef STAGE_B

    // epilogue: C/D layout col=lane&15, row=(lane>>4)*4+reg
#pragma unroll
    for (int i = 0; i < 8; ++i) {
#pragma unroll
        for (int j = 0; j < 4; ++j) {
#pragma unroll
            for (int r = 0; r < 4; ++r) {
                int row = row0 + wm + i * 16 + kq * 4 + r;
                int col = col0 + wn + j * 16 + fr;
                C[(size_t)row * NCOLS + col] = f2bf(acc[i][j][r]);
            }
        }
    }
}

// ---------------- Scan phase 1: per-chunk aggregates (A = prod a, Y = local state)
__global__ __launch_bounds__(256) void chunk_agg_kernel(const unsigned short* __restrict__ qkva,
                                                        float* __restrict__ Aagg,
                                                        float* __restrict__ Yagg) {
    const int c = blockIdx.x, b = blockIdx.y;
    const int d4 = threadIdx.x * 4;                  // channel group base (0..1020)
    const unsigned short* base = qkva + ((size_t)b * SEQ_N + c * CHUNK_L) * NCOLS;
    float s[4] = {0.f, 0.f, 0.f, 0.f};
    float A[4] = {1.f, 1.f, 1.f, 1.f};
#pragma unroll 4
    for (int n = 0; n < CHUNK_L; ++n) {
        const ushort4 kvu = *reinterpret_cast<const ushort4*>(base + (size_t)n * NCOLS + DIM + d4);
        const ushort4 au  = *reinterpret_cast<const ushort4*>(base + (size_t)n * NCOLS + 2 * DIM + d4);
        const float kv[4] = {bf2f(kvu.x), bf2f(kvu.y), bf2f(kvu.z), bf2f(kvu.w)};
        const float av[4] = {bf2f(au.x),  bf2f(au.y),  bf2f(au.z),  bf2f(au.w)};
#pragma unroll
        for (int j = 0; j < 4; ++j) {
            const float a = sigm(av[j]);
            s[j] = fmaf(a, s[j], kv[j]);
            A[j] *= a;
        }
    }
    const int idx = c * NCHANNEL + b * DIM + d4;
    float4 Ao, Yo;
    Ao.x = A[0]; Ao.y = A[1]; Ao.z = A[2]; Ao.w = A[3];
    Yo.x = s[0]; Yo.y = s[1]; Yo.z = s[2]; Yo.w = s[3];
    *reinterpret_cast<float4*>(&Aagg[idx]) = Ao;
    *reinterpret_cast<float4*>(&Yagg[idx]) = Yo;
}

// ---------------- Scan phase 2: sequential scan over chunk aggregates -> chunk entry state
__global__ __launch_bounds__(256) void agg_scan_kernel(const float* __restrict__ Aagg,
                                                       const float* __restrict__ Yagg,
                                                       float* __restrict__ Sin) {
    const int ch = blockIdx.x * 256 + threadIdx.x;   // 0..4095
    float s = 0.f;
#pragma unroll 8
    for (int c = 0; c < NCHUNK; ++c) {
        const float A = Aagg[c * NCHANNEL + ch];
        const float Y = Yagg[c * NCHANNEL + ch];
        Sin[c * NCHANNEL + ch] = s;
        s = fmaf(A, s, Y);
    }
}

// ---------------- Scan phase 3: rescan chunk with correct entry state, out = q*y
__global__ __launch_bounds__(256) void apply_kernel(const unsigned short* __restrict__ qkva,
                                                    const float* __restrict__ Sin,
                                                    float* __restrict__ out) {
    const int c = blockIdx.x, b = blockIdx.y;
    const int d4 = threadIdx.x * 4;
    const unsigned short* base = qkva + ((size_t)b * SEQ_N + c * CHUNK_L) * NCOLS;
    float* obase = out + ((size_t)b * SEQ_N + c * CHUNK_L) * DIM;
    const float4 s0 = *reinterpret_cast<const float4*>(&Sin[c * NCHANNEL + b * DIM + d4]);
    float s[4] = {s0.x, s0.y, s0.z, s0.w};
#pragma unroll 4
    for (int n = 0; n < CHUNK_L; ++n) {
        const ushort4 qu  = *reinterpret_cast<const ushort4*>(base + (size_t)n * NCOLS + d4);
        const ushort4 kvu = *reinterpret_cast<const ushort4*>(base + (size_t)n * NCOLS + DIM + d4);
        const ushort4 au  = *reinterpret_cast<const ushort4*>(base + (size_t)n * NCOLS + 2 * DIM + d4);
        const float kv[4] = {bf2f(kvu.x), bf2f(kvu.y), bf2f(kvu.z), bf2f(kvu.w)};
        const float av[4] = {bf2f(au.x),  bf2f(au.y),  bf2f(au.z),  bf2f(au.w)};
        const float q[4]  = {bf2f(qu.x),  bf2f(qu.y),  bf2f(qu.z),  bf2f(qu.w)};
        float4 o;
#pragma unroll
        for (int j = 0; j < 4; ++j) {
            const float a = sigm(av[j]);
            s[j] = fmaf(a, s[j], kv[j]);
        }
        o.x = q[0] * s[0]; o.y = q[1] * s[1]; o.z = q[2] * s[2]; o.w = q[3] * s[3];
        *reinterpret_cast<float4*>(&obase[(size_t)n * DIM + d4]) = o;
    }
}

extern "C" void kernel_launch(void* const* d_in, const int* in_sizes, int n_in,
                              void* d_out, int out_size, void* d_ws, size_t ws_size,
                              hipStream_t stream) {
    const float* x     = (const float*)d_in[0];   // [4,4096,1024]
    const float* w     = (const float*)d_in[1];   // [3072,1024]
    const float* gamma = (const float*)d_in[2];   // [1024]
    float* out = (float*)d_out;                   // [4,4096,1024]

    char* ws = (char*)d_ws;
    // workspace layout (bytes):
    unsigned short* wb   = (unsigned short*)(ws);                         // 3072*1024*2   = 6,291,456
    unsigned short* h    = (unsigned short*)(ws + 6291456);               // 16384*1024*2  = 33,554,432
    unsigned short* qkva = (unsigned short*)(ws + 39845888);              // 16384*3072*2  = 100,663,296
    // scan temporaries alias the h region (h is dead after the GEMM):
    // NCHUNK*NCHANNEL*4 = 256*4096*4 = 4,194,304 each
    float* Aagg = (float*)(ws + 6291456);
    float* Yagg = (float*)(ws + 6291456 + 4194304);
    float* Sin  = (float*)(ws + 6291456 + 8388608);

    pre_kernel<<<WCONV_BLOCKS + M_ROWS, 256, 0, stream>>>(w, wb, x, gamma, h);
    gemm256_kernel<<<(M_ROWS / 256) * (NCOLS / 256), 512, 0, stream>>>(h, wb, qkva);
    chunk_agg_kernel<<<dim3(NCHUNK, BATCH), 256, 0, stream>>>(qkva, Aagg, Yagg);
    agg_scan_kernel<<<NCHANNEL / 256, 256, 0, stream>>>(Aagg, Yagg, Sin);
    apply_kernel<<<dim3(NCHUNK, BATCH), 256, 0, stream>>>(qkva, Sin, out);
}